// Round 4
// baseline (2436.919 us; speedup 1.0000x reference)
//
#include <hip/hip_runtime.h>
#include <math.h>

#define EPSV 1e-4f
#define NSWEEP 10
#define NRT (99 * NSWEEP)
#define TOL2 5e-7f

// ---------- Kernel A: W = W1 @ W2 (400x200 @ 200x100 -> 400x100) ----------
__global__ __launch_bounds__(256) void kA(const float* __restrict__ W1,
                                          const float* __restrict__ W2,
                                          float* __restrict__ W) {
  int e = blockIdx.x * 256 + threadIdx.x;
  if (e >= 400 * 100) return;
  int i = e / 100, j = e - (e / 100) * 100;
  float s = 0.f;
#pragma unroll 4
  for (int k = 0; k < 200; ++k) s += W1[i * 200 + k] * W2[k * 100 + j];
  W[e] = s;
}

// ---------- Kernel B: Y[b] = x[b] @ W  (400x400 @ 400x100) ----------
__global__ __launch_bounds__(256) void kB(const float* __restrict__ x,
                                          const float* __restrict__ W,
                                          float* __restrict__ Y) {
  __shared__ float xs[16][41];
  __shared__ float ws[40][104];
  const int b = blockIdx.y, rt = blockIdx.x;
  const int tid = threadIdx.x;
  const int tc = tid & 31, tr = tid >> 5;
  const float* xb = x + (size_t)b * 160000 + (size_t)rt * 16 * 400;
  float acc[2][4] = {{0.f, 0.f, 0.f, 0.f}, {0.f, 0.f, 0.f, 0.f}};
  for (int k0 = 0; k0 < 400; k0 += 40) {
    for (int e = tid; e < 640; e += 256) {
      int r = e / 40, kk = e - r * 40;
      xs[r][kk] = xb[r * 400 + k0 + kk];
    }
    for (int e = tid; e < 4000; e += 256) {
      int kk = e / 100, j = e - kk * 100;
      ws[kk][j] = W[(k0 + kk) * 100 + j];
    }
    __syncthreads();
#pragma unroll 8
    for (int kk = 0; kk < 40; ++kk) {
      float a0 = xs[tr][kk], a1 = xs[tr + 8][kk];
      float b0 = ws[kk][tc], b1 = ws[kk][tc + 32], b2 = ws[kk][tc + 64];
      float b3 = (tc + 96 < 100) ? ws[kk][tc + 96] : 0.f;
      acc[0][0] += a0 * b0; acc[0][1] += a0 * b1; acc[0][2] += a0 * b2; acc[0][3] += a0 * b3;
      acc[1][0] += a1 * b0; acc[1][1] += a1 * b1; acc[1][2] += a1 * b2; acc[1][3] += a1 * b3;
    }
    __syncthreads();
  }
  float* Yb = Y + (size_t)b * 40000 + (size_t)rt * 1600;
#pragma unroll
  for (int rr = 0; rr < 2; ++rr) {
    int r = tr + 8 * rr;
#pragma unroll
    for (int u = 0; u < 4; ++u) {
      int c = tc + 32 * u;
      if (c < 100) Yb[r * 100 + c] = acc[rr][u];
    }
  }
}

// flat triu index (n=100) -> row
__device__ __forceinline__ int triu_row(int e) {
  int i = (int)((201.0f - sqrtf(40401.0f - 8.0f * (float)e)) * 0.5f);
  if (i < 0) i = 0;
  if (i > 99) i = 99;
  while (i > 0 && (201 * i - i * i) > 2 * e) --i;
  while ((201 * (i + 1) - (i + 1) * (i + 1)) <= 2 * e) ++i;
  return i;
}
// flat triu index (n=50) -> row
__device__ __forceinline__ int triu50_row(int e) {
  int i = (int)((101.0f - sqrtf(10201.0f - 8.0f * (float)e)) * 0.5f);
  if (i < 0) i = 0;
  if (i > 49) i = 49;
  while (i > 0 && (101 * i - i * i) > 2 * e) --i;
  while ((101 * (i + 1) - (i + 1) * (i + 1)) <= 2 * e) ++i;
  return i;
}
__device__ __forceinline__ int cano(int i, int j) { return (i < j) ? i * 100 + j : j * 100 + i; }

// angle phase for round rr (within-sweep index): executed by all 64 lanes of wave 15
__device__ __forceinline__ void angle_phase(const float* A, float4* csrow, int rr, int tid,
                                            float* offacc_slot, int* nrot_slot) {
  int k = tid - 960;
  float off2 = 0.f;
  bool rot = false;
  if (k < 50) {
    int p, q;
    if (k == 0) { p = 99; q = rr; }
    else {
      p = rr + k; if (p >= 99) p -= 99;
      q = rr - k; if (q < 0) q += 99;
    }
    float app = A[p * 100 + p], aqq = A[q * 100 + q];
    float apq = A[cano(p, q)];
    off2 = apq * apq;
    float c = 1.f, s = 0.f;
    if (off2 > 1e-12f * fabsf(app * aqq) + 1e-30f) {
      float tau = (aqq - app) / (2.f * apq);
      float t = copysignf(1.f, tau) / (fabsf(tau) + sqrtf(1.f + tau * tau));
      c = 1.f / sqrtf(1.f + t * t);
      s = t * c;
      rot = true;
    }
    csrow[k] = make_float4(c, s, __int_as_float(p), __int_as_float(q));
  }
  unsigned long long bal = __ballot(rot);
#pragma unroll
  for (int off = 32; off > 0; off >>= 1) off2 += __shfl_down(off2, off);
  if (k == 0) {
    *nrot_slot = (bal != 0ULL) ? 1 : 0;
    *offacc_slot += off2;
  }
}

// ---------- Kernel C: per-batch  M = W^T Y_b ; logm via Jacobi ; classifier ----------
__global__ __launch_bounds__(1024) void kC(const float* __restrict__ W,
                                           const float* __restrict__ Y,
                                           const float* __restrict__ Wc,
                                           const float* __restrict__ bcv,
                                           float* __restrict__ out) {
  __shared__ float A[10000];    // pitch 100; only canonical triangle valid during Jacobi
  __shared__ float Vt[10000];   // pitch 100; rows of Vt are eigencolumns of V
  __shared__ float4 cs4[2][50]; // (c, s, p-bits, q-bits), double-buffered
  __shared__ float lvec[100];
  __shared__ float red[16][12];
  __shared__ float offacc[NSWEEP];
  __shared__ int nrot[2];

  const int b = blockIdx.x, tid = threadIdx.x;
  const int q4 = tid & 31;
  const int r32 = tid >> 5;

  // ---- M = W^T @ Y_b  into A (stage K-chunks of 40 through Vt's storage) ----
  {
    float* Wst = Vt;          // [40][104]
    float* Yst = Vt + 4160;   // [40][104]
    const float* Yb = Y + (size_t)b * 40000;
    float acc[4][4];
#pragma unroll
    for (int m = 0; m < 4; ++m) acc[m][0] = acc[m][1] = acc[m][2] = acc[m][3] = 0.f;
    for (int k0 = 0; k0 < 400; k0 += 40) {
      for (int e = tid; e < 4000; e += 1024) {
        int kk = e / 100, j = e - kk * 100;
        Wst[kk * 104 + j] = W[(k0 + kk) * 100 + j];
        Yst[kk * 104 + j] = Yb[(k0 + kk) * 100 + j];
      }
      __syncthreads();
      for (int kk = 0; kk < 40; ++kk) {
        float y0 = Yst[kk * 104 + q4], y1 = Yst[kk * 104 + q4 + 32], y2 = Yst[kk * 104 + q4 + 64];
        float y3 = (q4 + 96 < 100) ? Yst[kk * 104 + q4 + 96] : 0.f;
#pragma unroll
        for (int m = 0; m < 4; ++m) {
          int p = r32 + 32 * m;
          if (p < 100) {
            float w = Wst[kk * 104 + p];
            acc[m][0] += w * y0; acc[m][1] += w * y1; acc[m][2] += w * y2; acc[m][3] += w * y3;
          }
        }
      }
      __syncthreads();
    }
#pragma unroll
    for (int m = 0; m < 4; ++m) {
      int p = r32 + 32 * m;
      if (p < 100) {
        A[p * 100 + q4] = acc[m][0];
        A[p * 100 + q4 + 32] = acc[m][1];
        A[p * 100 + q4 + 64] = acc[m][2];
        if (q4 + 96 < 100) A[p * 100 + q4 + 96] = acc[m][3];
      }
    }
  }
  // Vt = I; init offacc
  for (int e = tid; e < 10000; e += 1024) {
    int r = e / 100, c = e - r * 100;
    Vt[e] = (r == c) ? 1.f : 0.f;
  }
  if (tid < NSWEEP) offacc[tid] = 0.f;
  __syncthreads();
  // symmetrize into canonical triangle (i<=j) only
  for (int e = tid; e < 5050; e += 1024) {
    int i = triu_row(e);
    int j = i + (e - ((201 * i - i * i) >> 1));
    A[i * 100 + j] = 0.5f * (A[i * 100 + j] + A[j * 100 + i]);
  }
  __syncthreads();
  // prologue: angles for round 0
  if (tid >= 960) angle_phase(A, cs4[0], 0, tid, &offacc[0], &nrot[0]);
  __syncthreads();

  // ---- cyclic Jacobi ----
  for (int r = 0; r < NRT; ++r) {
    const int cur = r & 1, nxt = cur ^ 1;
    // phase 1: A-update over canonical-triangle block pairs (a<=b), 1275 items
    if (nrot[cur]) {
      const float4* cs = cs4[cur];
      for (int e = tid; e < 1275; e += 1024) {
        int a = triu50_row(e);
        int bq = a + (e - ((101 * a - a * a) >> 1));
        float4 ta = cs[a], tb = cs[bq];
        float sa = ta.y, sb = tb.y;
        if (sa == 0.f && sb == 0.f) continue;
        float ca = ta.x, cb = tb.x;
        int pa = __float_as_int(ta.z), qa = __float_as_int(ta.w);
        int pb = __float_as_int(tb.z), qb = __float_as_int(tb.w);
        float m00 = A[cano(pa, pb)];
        float m01 = A[cano(pa, qb)];
        float m11 = A[cano(qa, qb)];
        float m10 = (a == bq) ? m01 : A[cano(qa, pb)];
        float t00 = ca * m00 - sa * m10;
        float t01 = ca * m01 - sa * m11;
        float t10 = sa * m00 + ca * m10;
        float t11 = sa * m01 + ca * m11;
        A[cano(pa, pb)] = cb * t00 - sb * t01;
        A[cano(pa, qb)] = sb * t00 + cb * t01;
        if (a != bq) A[cano(qa, pb)] = cb * t10 - sb * t11;
        A[cano(qa, qb)] = sb * t10 + cb * t11;
      }
    }
    __syncthreads();
    // phase 2: Vt row rotations (float4) + next round's angles on wave 15
    if (nrot[cur]) {
      const float4* cs = cs4[cur];
      for (int e = tid; e < 1250; e += 1024) {
        int pr = e / 25, k4 = (e - pr * 25) << 2;
        float4 t = cs[pr];
        float s = t.y;
        if (s != 0.f) {
          float c = t.x;
          float4* vp = (float4*)&Vt[__float_as_int(t.z) * 100 + k4];
          float4* vq = (float4*)&Vt[__float_as_int(t.w) * 100 + k4];
          float4 a4 = *vp, b4 = *vq, n4, m4;
          n4.x = c * a4.x - s * b4.x; n4.y = c * a4.y - s * b4.y;
          n4.z = c * a4.z - s * b4.z; n4.w = c * a4.w - s * b4.w;
          m4.x = s * a4.x + c * b4.x; m4.y = s * a4.y + c * b4.y;
          m4.z = s * a4.z + c * b4.z; m4.w = s * a4.w + c * b4.w;
          *vp = n4; *vq = m4;
        }
      }
    }
    if (tid >= 960 && r + 1 < NRT)
      angle_phase(A, cs4[nxt], (r + 1) % 99, tid, &offacc[(r + 1) / 99], &nrot[nxt]);
    __syncthreads();
    if ((r % 99) == 98 && offacc[r / 99] < TOL2) break;  // uniform: LDS read post-barrier
  }

  // ---- eigenvalue log ----
  for (int i2 = tid; i2 < 100; i2 += 1024) lvec[i2] = logf(fmaxf(A[i2 * 100 + i2], EPSV));
  __syncthreads();

  // ---- H = sum_p l_p * Vt[p][i] * Vt[p][j]  into A (full square) ----
  {
    float hacc[4][4];
#pragma unroll
    for (int m = 0; m < 4; ++m) hacc[m][0] = hacc[m][1] = hacc[m][2] = hacc[m][3] = 0.f;
    for (int p = 0; p < 100; ++p) {
      float l = lvec[p];
      const float* vr = Vt + p * 100;
      float vj0 = vr[q4], vj1 = vr[q4 + 32], vj2 = vr[q4 + 64];
      float vj3 = (q4 + 96 < 100) ? vr[q4 + 96] : 0.f;
#pragma unroll
      for (int m = 0; m < 4; ++m) {
        int i = r32 + 32 * m;
        if (i < 100) {
          float vil = vr[i] * l;
          hacc[m][0] += vil * vj0; hacc[m][1] += vil * vj1;
          hacc[m][2] += vil * vj2; hacc[m][3] += vil * vj3;
        }
      }
    }
    __syncthreads();
#pragma unroll
    for (int m = 0; m < 4; ++m) {
      int i = r32 + 32 * m;
      if (i < 100) {
        A[i * 100 + q4] = hacc[m][0];
        A[i * 100 + q4 + 32] = hacc[m][1];
        A[i * 100 + q4 + 64] = hacc[m][2];
        if (q4 + 96 < 100) A[i * 100 + q4 + 96] = hacc[m][3];
      }
    }
  }
  __syncthreads();

  // ---- classifier: out[b][c] = bc[c] + sum_triu H[i][j] * Wc[c][e] ----
  float accc[10];
#pragma unroll
  for (int c = 0; c < 10; ++c) accc[c] = 0.f;
  for (int e = tid; e < 5050; e += 1024) {
    int i = triu_row(e);
    int j = i + (e - ((201 * i - i * i) >> 1));
    float h = A[i * 100 + j];
#pragma unroll
    for (int c = 0; c < 10; ++c) accc[c] += h * Wc[c * 5050 + e];
  }
  const int lane = tid & 63, wv = tid >> 6;
#pragma unroll
  for (int c = 0; c < 10; ++c) {
    float v = accc[c];
#pragma unroll
    for (int off = 32; off > 0; off >>= 1) v += __shfl_down(v, off);
    if (lane == 0) red[wv][c] = v;
  }
  __syncthreads();
  if (tid < 10) {
    float s = bcv[tid];
#pragma unroll
    for (int w = 0; w < 16; ++w) s += red[w][tid];
    out[b * 10 + tid] = s;
  }
}

extern "C" void kernel_launch(void* const* d_in, const int* in_sizes, int n_in,
                              void* d_out, int out_size, void* d_ws, size_t ws_size,
                              hipStream_t stream) {
  const float* x = (const float*)d_in[0];
  const float* W1 = (const float*)d_in[1];
  const float* W2 = (const float*)d_in[2];
  const float* Wc = (const float*)d_in[3];
  const float* bc = (const float*)d_in[4];
  float* out = (float*)d_out;

  float* W = (float*)d_ws;        // 400*100 floats
  float* Y = W + 40000;           // 256*400*100 floats (~41 MB)

  kA<<<157, 256, 0, stream>>>(W1, W2, W);
  kB<<<dim3(25, 256), 256, 0, stream>>>(x, W, Y);
  kC<<<256, 1024, 0, stream>>>(W, Y, Wc, bc, out);
}

// Round 5
// 2043.685 us; speedup vs baseline: 1.1924x; 1.1924x over previous
//
#include <hip/hip_runtime.h>
#include <math.h>

#define EPSV 1e-4f
#define NSWEEP 10
#define NRT (99 * NSWEEP)

// ---------- Kernel A: W = W1 @ W2 (400x200 @ 200x100 -> 400x100) ----------
__global__ __launch_bounds__(256) void kA(const float* __restrict__ W1,
                                          const float* __restrict__ W2,
                                          float* __restrict__ W) {
  int e = blockIdx.x * 256 + threadIdx.x;
  if (e >= 400 * 100) return;
  int i = e / 100, j = e - (e / 100) * 100;
  float s = 0.f;
#pragma unroll 4
  for (int k = 0; k < 200; ++k) s += W1[i * 200 + k] * W2[k * 100 + j];
  W[e] = s;
}

// ---------- Kernel B: Y[b] = x[b] @ W  (400x400 @ 400x100) ----------
__global__ __launch_bounds__(256) void kB(const float* __restrict__ x,
                                          const float* __restrict__ W,
                                          float* __restrict__ Y) {
  __shared__ float xs[16][41];
  __shared__ float ws[40][104];
  const int b = blockIdx.y, rt = blockIdx.x;
  const int tid = threadIdx.x;
  const int tc = tid & 31, tr = tid >> 5;
  const float* xb = x + (size_t)b * 160000 + (size_t)rt * 16 * 400;
  float acc[2][4] = {{0.f, 0.f, 0.f, 0.f}, {0.f, 0.f, 0.f, 0.f}};
  for (int k0 = 0; k0 < 400; k0 += 40) {
    for (int e = tid; e < 640; e += 256) {
      int r = e / 40, kk = e - r * 40;
      xs[r][kk] = xb[r * 400 + k0 + kk];
    }
    for (int e = tid; e < 4000; e += 256) {
      int kk = e / 100, j = e - kk * 100;
      ws[kk][j] = W[(k0 + kk) * 100 + j];
    }
    __syncthreads();
#pragma unroll 8
    for (int kk = 0; kk < 40; ++kk) {
      float a0 = xs[tr][kk], a1 = xs[tr + 8][kk];
      float b0 = ws[kk][tc], b1 = ws[kk][tc + 32], b2 = ws[kk][tc + 64];
      float b3 = (tc + 96 < 100) ? ws[kk][tc + 96] : 0.f;
      acc[0][0] += a0 * b0; acc[0][1] += a0 * b1; acc[0][2] += a0 * b2; acc[0][3] += a0 * b3;
      acc[1][0] += a1 * b0; acc[1][1] += a1 * b1; acc[1][2] += a1 * b2; acc[1][3] += a1 * b3;
    }
    __syncthreads();
  }
  float* Yb = Y + (size_t)b * 40000 + (size_t)rt * 1600;
#pragma unroll
  for (int rr = 0; rr < 2; ++rr) {
    int r = tr + 8 * rr;
#pragma unroll
    for (int u = 0; u < 4; ++u) {
      int c = tc + 32 * u;
      if (c < 100) Yb[r * 100 + c] = acc[rr][u];
    }
  }
}

// flat triu index (n=100) -> row (one-off use in symmetrize)
__device__ __forceinline__ int triu_row(int e) {
  int i = (int)((201.0f - sqrtf(40401.0f - 8.0f * (float)e)) * 0.5f);
  if (i < 0) i = 0;
  if (i > 99) i = 99;
  while (i > 0 && (201 * i - i * i) > 2 * e) --i;
  while ((201 * (i + 1) - (i + 1) * (i + 1)) <= 2 * e) ++i;
  return i;
}

// ---------- Kernel C: M = W^T Y_b ; logm via ONE-SIDED Jacobi ; classifier ----------
// B = M * (accumulated rotations). Columns of B orthogonalize; then
// lambda_p = ||b_p||, u_p = b_p/||b_p||, H = sum_p (log l_p / ||b_p||^2) b_p b_p^T.
__global__ __launch_bounds__(1024) void kC(const float* __restrict__ W,
                                           const float* __restrict__ Y,
                                           const float* __restrict__ Wc,
                                           const float* __restrict__ bcv,
                                           float* __restrict__ out) {
  __shared__ float B[10000];      // column-major: column p at B + p*100 (400B, 16B-aligned)
  __shared__ float stage[8320];   // GEMM staging; later Hf[5050] (triu-flat H)
  __shared__ float4 cs4[50];      // (c, s, p*100 bits, q*100 bits)
  __shared__ float sfin[100];
  __shared__ float red[16][12];
  __shared__ int rotacc[50];
  __shared__ int brk;

  const int b = blockIdx.x, tid = threadIdx.x;
  const int q4 = tid & 31;
  const int r32 = tid >> 5;
  const int g = tid >> 4, lane = tid & 15;  // 64 groups of 16

  // ---- M = W^T @ Y_b  into B ----
  {
    float* Wst = stage;          // [40][104]
    float* Yst = stage + 4160;   // [40][104]
    const float* Yb = Y + (size_t)b * 40000;
    float acc[4][4];
#pragma unroll
    for (int m = 0; m < 4; ++m) acc[m][0] = acc[m][1] = acc[m][2] = acc[m][3] = 0.f;
    for (int k0 = 0; k0 < 400; k0 += 40) {
      for (int e = tid; e < 4000; e += 1024) {
        int kk = e / 100, j = e - kk * 100;
        Wst[kk * 104 + j] = W[(k0 + kk) * 100 + j];
        Yst[kk * 104 + j] = Yb[(k0 + kk) * 100 + j];
      }
      __syncthreads();
      for (int kk = 0; kk < 40; ++kk) {
        float y0 = Yst[kk * 104 + q4], y1 = Yst[kk * 104 + q4 + 32], y2 = Yst[kk * 104 + q4 + 64];
        float y3 = (q4 + 96 < 100) ? Yst[kk * 104 + q4 + 96] : 0.f;
#pragma unroll
        for (int m = 0; m < 4; ++m) {
          int p = r32 + 32 * m;
          if (p < 100) {
            float w = Wst[kk * 104 + p];
            acc[m][0] += w * y0; acc[m][1] += w * y1; acc[m][2] += w * y2; acc[m][3] += w * y3;
          }
        }
      }
      __syncthreads();
    }
#pragma unroll
    for (int m = 0; m < 4; ++m) {
      int p = r32 + 32 * m;
      if (p < 100) {
        B[p * 100 + q4] = acc[m][0];
        B[p * 100 + q4 + 32] = acc[m][1];
        B[p * 100 + q4 + 64] = acc[m][2];
        if (q4 + 96 < 100) B[p * 100 + q4 + 96] = acc[m][3];
      }
    }
  }
  if (tid < 50) rotacc[tid] = 0;
  __syncthreads();
  // symmetrize both triangles (row-major symmetric == column-major)
  for (int e = tid; e < 5050; e += 1024) {
    int i = triu_row(e);
    int j = i + (e - ((201 * i - i * i) >> 1));
    float av = 0.5f * (B[i * 100 + j] + B[j * 100 + i]);
    B[i * 100 + j] = av;
    B[j * 100 + i] = av;
  }
  __syncthreads();

  // ---- one-sided cyclic Jacobi ----
  for (int r = 0; r < NRT; ++r) {
    const int rr = r % 99;
    // dot phase: group g (16 threads) handles pair g of round rr
    if (g < 50) {
      int p, q;
      if (g == 0) { p = 99; q = rr; }
      else {
        p = rr + g; if (p >= 99) p -= 99;
        q = rr - g; if (q < 0) q += 99;
      }
      const float* bp = B + p * 100;
      const float* bq = B + q * 100;
      float4 a4 = *(const float4*)(bp + 4 * lane);
      float4 b4 = *(const float4*)(bq + 4 * lane);
      float d = a4.x * b4.x + a4.y * b4.y + a4.z * b4.z + a4.w * b4.w;
      float pn = a4.x * a4.x + a4.y * a4.y + a4.z * a4.z + a4.w * a4.w;
      float qn = b4.x * b4.x + b4.y * b4.y + b4.z * b4.z + b4.w * b4.w;
      if (lane < 9) {  // chunks 16..24
        float4 a8 = *(const float4*)(bp + 4 * lane + 64);
        float4 b8 = *(const float4*)(bq + 4 * lane + 64);
        d += a8.x * b8.x + a8.y * b8.y + a8.z * b8.z + a8.w * b8.w;
        pn += a8.x * a8.x + a8.y * a8.y + a8.z * a8.z + a8.w * a8.w;
        qn += b8.x * b8.x + b8.y * b8.y + b8.z * b8.z + b8.w * b8.w;
      }
#pragma unroll
      for (int off = 1; off <= 8; off <<= 1) {
        d += __shfl_xor(d, off);
        pn += __shfl_xor(pn, off);
        qn += __shfl_xor(qn, off);
      }
      // implicit two-sided Jacobi on M^2: app=pn, aqq=qn, apq=d
      float c = 1.f, s = 0.f;
      int rot = (d * d > 1e-12f * pn * qn + 1e-30f) ? 1 : 0;
      if (rot) {
        float tau = (qn - pn) / (2.f * d);
        float t = copysignf(1.f, tau) / (fabsf(tau) + sqrtf(1.f + tau * tau));
        c = 1.f / sqrtf(1.f + t * t);
        s = t * c;
      }
      if (lane == 0) {
        cs4[g] = make_float4(c, s, __int_as_float(p * 100), __int_as_float(q * 100));
        rotacc[g] += rot;
      }
    }
    __syncthreads();
    // rotate phase: 50 pairs x 25 float4 chunks = 1250 items, all b128
    for (int e = tid; e < 1250; e += 1024) {
      int pr = e / 25, k4 = (e - pr * 25) << 2;
      float4 t4 = cs4[pr];
      float s = t4.y;
      if (s != 0.f) {
        float c = t4.x;
        float4* vp = (float4*)(B + __float_as_int(t4.z) + k4);
        float4* vq = (float4*)(B + __float_as_int(t4.w) + k4);
        float4 x4 = *vp, y4 = *vq, n4, m4;
        n4.x = c * x4.x - s * y4.x; n4.y = c * x4.y - s * y4.y;
        n4.z = c * x4.z - s * y4.z; n4.w = c * x4.w - s * y4.w;
        m4.x = s * x4.x + c * y4.x; m4.y = s * x4.y + c * y4.y;
        m4.z = s * x4.z + c * y4.z; m4.w = s * x4.w + c * y4.w;
        *vp = n4; *vq = m4;
      }
    }
    // sweep end: count rotations; reset; set break flag (wave 0 only)
    if (rr == 98 && tid < 64) {
      int v = (tid < 50) ? rotacc[tid] : 0;
#pragma unroll
      for (int off = 32; off > 0; off >>= 1) v += __shfl_xor(v, off);
      if (tid == 0) brk = (v == 0) ? 1 : 0;
      if (tid < 50) rotacc[tid] = 0;
    }
    __syncthreads();
    if (rr == 98 && brk) break;
  }

  // ---- scales: sfin[p] = log(max(||b_p||, EPSV)) / ||b_p||^2 ----
  for (int col = g; col < 100; col += 64) {
    const float* bp = B + col * 100;
    float4 a4 = *(const float4*)(bp + 4 * lane);
    float n = a4.x * a4.x + a4.y * a4.y + a4.z * a4.z + a4.w * a4.w;
    if (lane < 9) {
      float4 a8 = *(const float4*)(bp + 4 * lane + 64);
      n += a8.x * a8.x + a8.y * a8.y + a8.z * a8.z + a8.w * a8.w;
    }
#pragma unroll
    for (int off = 1; off <= 8; off <<= 1) n += __shfl_xor(n, off);
    if (lane == 0) sfin[col] = logf(fmaxf(sqrtf(n), EPSV)) / n;
  }
  __syncthreads();

  // ---- Hf (triu flat) = sum_p sfin[p] * b_p b_p^T ----
  float* Hf = stage;
  {
    float hacc[4][4];
#pragma unroll
    for (int m = 0; m < 4; ++m) hacc[m][0] = hacc[m][1] = hacc[m][2] = hacc[m][3] = 0.f;
    for (int p = 0; p < 100; ++p) {
      float l = sfin[p];
      const float* vr = B + p * 100;
      float vj0 = vr[q4], vj1 = vr[q4 + 32], vj2 = vr[q4 + 64];
      float vj3 = (q4 + 96 < 100) ? vr[q4 + 96] : 0.f;
#pragma unroll
      for (int m = 0; m < 4; ++m) {
        int i = r32 + 32 * m;
        if (i < 100) {
          float vil = vr[i] * l;
          hacc[m][0] += vil * vj0; hacc[m][1] += vil * vj1;
          hacc[m][2] += vil * vj2; hacc[m][3] += vil * vj3;
        }
      }
    }
    __syncthreads();  // all reads of stage (none) done; B reads complete before... (Hf != B, barrier for stage reuse safety)
#pragma unroll
    for (int m = 0; m < 4; ++m) {
      int i = r32 + 32 * m;
      if (i >= 100) continue;
#pragma unroll
      for (int n = 0; n < 4; ++n) {
        int j = q4 + 32 * n;
        if (j < 100 && i <= j) Hf[((201 * i - i * i) >> 1) + (j - i)] = hacc[m][n];
      }
    }
  }
  __syncthreads();

  // ---- classifier: out[b][c] = bc[c] + sum_e Hf[e] * Wc[c][e] ----
  float accc[10];
#pragma unroll
  for (int c = 0; c < 10; ++c) accc[c] = 0.f;
  for (int e = tid; e < 5050; e += 1024) {
    float h = Hf[e];
#pragma unroll
    for (int c = 0; c < 10; ++c) accc[c] += h * Wc[c * 5050 + e];
  }
  const int lane64 = tid & 63, wv = tid >> 6;
#pragma unroll
  for (int c = 0; c < 10; ++c) {
    float v = accc[c];
#pragma unroll
    for (int off = 32; off > 0; off >>= 1) v += __shfl_down(v, off);
    if (lane64 == 0) red[wv][c] = v;
  }
  __syncthreads();
  if (tid < 10) {
    float s = bcv[tid];
#pragma unroll
    for (int w = 0; w < 16; ++w) s += red[w][tid];
    out[b * 10 + tid] = s;
  }
}

extern "C" void kernel_launch(void* const* d_in, const int* in_sizes, int n_in,
                              void* d_out, int out_size, void* d_ws, size_t ws_size,
                              hipStream_t stream) {
  const float* x = (const float*)d_in[0];
  const float* W1 = (const float*)d_in[1];
  const float* W2 = (const float*)d_in[2];
  const float* Wc = (const float*)d_in[3];
  const float* bc = (const float*)d_in[4];
  float* out = (float*)d_out;

  float* W = (float*)d_ws;        // 400*100 floats
  float* Y = W + 40000;           // 256*400*100 floats (~41 MB)

  kA<<<157, 256, 0, stream>>>(W1, W2, W);
  kB<<<dim3(25, 256), 256, 0, stream>>>(x, W, Y);
  kC<<<256, 1024, 0, stream>>>(W, Y, Wc, bc, out);
}

// Round 6
// 1417.608 us; speedup vs baseline: 1.7190x; 1.4416x over previous
//
#include <hip/hip_runtime.h>
#include <math.h>

#define EPSV 1e-4f
#define NSWEEP 10
#define NRT (99 * NSWEEP)

// ---------- Kernel A: W = W1 @ W2 (400x200 @ 200x100 -> 400x100) ----------
__global__ __launch_bounds__(256) void kA(const float* __restrict__ W1,
                                          const float* __restrict__ W2,
                                          float* __restrict__ W) {
  int e = blockIdx.x * 256 + threadIdx.x;
  if (e >= 400 * 100) return;
  int i = e / 100, j = e - (e / 100) * 100;
  float s = 0.f;
#pragma unroll 4
  for (int k = 0; k < 200; ++k) s += W1[i * 200 + k] * W2[k * 100 + j];
  W[e] = s;
}

// ---------- Kernel B: Y[b] = x[b] @ W  (400x400 @ 400x100) ----------
__global__ __launch_bounds__(256) void kB(const float* __restrict__ x,
                                          const float* __restrict__ W,
                                          float* __restrict__ Y) {
  __shared__ float xs[16][41];
  __shared__ float ws[40][104];
  const int b = blockIdx.y, rt = blockIdx.x;
  const int tid = threadIdx.x;
  const int tc = tid & 31, tr = tid >> 5;
  const float* xb = x + (size_t)b * 160000 + (size_t)rt * 16 * 400;
  float acc[2][4] = {{0.f, 0.f, 0.f, 0.f}, {0.f, 0.f, 0.f, 0.f}};
  for (int k0 = 0; k0 < 400; k0 += 40) {
    for (int e = tid; e < 640; e += 256) {
      int r = e / 40, kk = e - r * 40;
      xs[r][kk] = xb[r * 400 + k0 + kk];
    }
    for (int e = tid; e < 4000; e += 256) {
      int kk = e / 100, j = e - kk * 100;
      ws[kk][j] = W[(k0 + kk) * 100 + j];
    }
    __syncthreads();
#pragma unroll 8
    for (int kk = 0; kk < 40; ++kk) {
      float a0 = xs[tr][kk], a1 = xs[tr + 8][kk];
      float b0 = ws[kk][tc], b1 = ws[kk][tc + 32], b2 = ws[kk][tc + 64];
      float b3 = (tc + 96 < 100) ? ws[kk][tc + 96] : 0.f;
      acc[0][0] += a0 * b0; acc[0][1] += a0 * b1; acc[0][2] += a0 * b2; acc[0][3] += a0 * b3;
      acc[1][0] += a1 * b0; acc[1][1] += a1 * b1; acc[1][2] += a1 * b2; acc[1][3] += a1 * b3;
    }
    __syncthreads();
  }
  float* Yb = Y + (size_t)b * 40000 + (size_t)rt * 1600;
#pragma unroll
  for (int rr = 0; rr < 2; ++rr) {
    int r = tr + 8 * rr;
#pragma unroll
    for (int u = 0; u < 4; ++u) {
      int c = tc + 32 * u;
      if (c < 100) Yb[r * 100 + c] = acc[rr][u];
    }
  }
}

// flat triu index (n=100) -> row (one-off use in symmetrize)
__device__ __forceinline__ int triu_row(int e) {
  int i = (int)((201.0f - sqrtf(40401.0f - 8.0f * (float)e)) * 0.5f);
  if (i < 0) i = 0;
  if (i > 99) i = 99;
  while (i > 0 && (201 * i - i * i) > 2 * e) --i;
  while ((201 * (i + 1) - (i + 1) * (i + 1)) <= 2 * e) ++i;
  return i;
}

// ---------- Kernel C: M = W^T Y_b ; logm via ONE-SIDED Jacobi (fused) ; classifier ----------
__global__ __launch_bounds__(1024) void kC(const float* __restrict__ W,
                                           const float* __restrict__ Y,
                                           const float* __restrict__ Wc,
                                           const float* __restrict__ bcv,
                                           float* __restrict__ out) {
  __shared__ float B[10000];      // column-major: column p at B + p*100
  __shared__ float stage[8320];   // GEMM staging; later Hf[5050]
  __shared__ float nrm[100];      // maintained squared column norms
  __shared__ float sfin[100];
  __shared__ float red[16][12];
  __shared__ int nrotsw[NSWEEP];

  const int b = blockIdx.x, tid = threadIdx.x;
  const int q4 = tid & 31;
  const int r32 = tid >> 5;
  const int g = tid >> 4, lane = tid & 15;  // 64 groups of 16 (wave-aligned)

  // ---- M = W^T @ Y_b  into B ----
  {
    float* Wst = stage;          // [40][104]
    float* Yst = stage + 4160;   // [40][104]
    const float* Yb = Y + (size_t)b * 40000;
    float acc[4][4];
#pragma unroll
    for (int m = 0; m < 4; ++m) acc[m][0] = acc[m][1] = acc[m][2] = acc[m][3] = 0.f;
    for (int k0 = 0; k0 < 400; k0 += 40) {
      for (int e = tid; e < 4000; e += 1024) {
        int kk = e / 100, j = e - kk * 100;
        Wst[kk * 104 + j] = W[(k0 + kk) * 100 + j];
        Yst[kk * 104 + j] = Yb[(k0 + kk) * 100 + j];
      }
      __syncthreads();
      for (int kk = 0; kk < 40; ++kk) {
        float y0 = Yst[kk * 104 + q4], y1 = Yst[kk * 104 + q4 + 32], y2 = Yst[kk * 104 + q4 + 64];
        float y3 = (q4 + 96 < 100) ? Yst[kk * 104 + q4 + 96] : 0.f;
#pragma unroll
        for (int m = 0; m < 4; ++m) {
          int p = r32 + 32 * m;
          if (p < 100) {
            float w = Wst[kk * 104 + p];
            acc[m][0] += w * y0; acc[m][1] += w * y1; acc[m][2] += w * y2; acc[m][3] += w * y3;
          }
        }
      }
      __syncthreads();
    }
#pragma unroll
    for (int m = 0; m < 4; ++m) {
      int p = r32 + 32 * m;
      if (p < 100) {
        B[p * 100 + q4] = acc[m][0];
        B[p * 100 + q4 + 32] = acc[m][1];
        B[p * 100 + q4 + 64] = acc[m][2];
        if (q4 + 96 < 100) B[p * 100 + q4 + 96] = acc[m][3];
      }
    }
  }
  if (tid < NSWEEP) nrotsw[tid] = 0;
  __syncthreads();
  // symmetrize both triangles
  for (int e = tid; e < 5050; e += 1024) {
    int i = triu_row(e);
    int j = i + (e - ((201 * i - i * i) >> 1));
    float av = 0.5f * (B[i * 100 + j] + B[j * 100 + i]);
    B[i * 100 + j] = av;
    B[j * 100 + i] = av;
  }
  __syncthreads();
  // initial squared norms (group g covers columns g, g+64)
  for (int col = g; col < 100; col += 64) {
    const float* bp = B + col * 100;
    float4 a4 = *(const float4*)(bp + 4 * lane);
    float n = a4.x * a4.x + a4.y * a4.y + a4.z * a4.z + a4.w * a4.w;
    if (lane < 9) {
      float4 a8 = *(const float4*)(bp + 64 + 4 * lane);
      n += a8.x * a8.x + a8.y * a8.y + a8.z * a8.z + a8.w * a8.w;
    }
#pragma unroll
    for (int off = 1; off <= 8; off <<= 1) n += __shfl_xor(n, off);
    if (lane == 0) nrm[col] = n;
  }
  __syncthreads();

  // ---- one-sided cyclic Jacobi: fused dot+rotate, 1 barrier/round ----
  for (int r = 0; r < NRT; ++r) {
    const int rr = r % 99;
    const int sweep = r / 99;
    if (g < 50) {
      int p, q;
      if (g == 0) { p = 99; q = rr; }
      else {
        p = rr + g; if (p >= 99) p -= 99;
        q = rr - g; if (q < 0) q += 99;
      }
      float* bp = B + p * 100;
      float* bq = B + q * 100;
      // load both columns into group registers; accumulate dot
      float4 a4 = *(const float4*)(bp + 4 * lane);
      float4 b4 = *(const float4*)(bq + 4 * lane);
      float4 a8 = make_float4(0.f, 0.f, 0.f, 0.f), b8 = a8;
      float d = a4.x * b4.x + a4.y * b4.y + a4.z * b4.z + a4.w * b4.w;
      if (lane < 9) {
        a8 = *(const float4*)(bp + 64 + 4 * lane);
        b8 = *(const float4*)(bq + 64 + 4 * lane);
        d += a8.x * b8.x + a8.y * b8.y + a8.z * b8.z + a8.w * b8.w;
      }
#pragma unroll
      for (int off = 1; off <= 8; off <<= 1) d += __shfl_xor(d, off);
      float pn = nrm[p], qn = nrm[q];
      if (d * d > 1e-11f * pn * qn + 1e-30f) {  // group-uniform branch
        float tau = (qn - pn) / (2.f * d);
        float t = copysignf(1.f, tau) / (fabsf(tau) + sqrtf(1.f + tau * tau));
        float c = 1.f / sqrtf(1.f + t * t);
        float s = t * c;
        float4 n4, m4;
        n4.x = c * a4.x - s * b4.x; n4.y = c * a4.y - s * b4.y;
        n4.z = c * a4.z - s * b4.z; n4.w = c * a4.w - s * b4.w;
        m4.x = s * a4.x + c * b4.x; m4.y = s * a4.y + c * b4.y;
        m4.z = s * a4.z + c * b4.z; m4.w = s * a4.w + c * b4.w;
        *(float4*)(bp + 4 * lane) = n4;
        *(float4*)(bq + 4 * lane) = m4;
        if (lane < 9) {
          n4.x = c * a8.x - s * b8.x; n4.y = c * a8.y - s * b8.y;
          n4.z = c * a8.z - s * b8.z; n4.w = c * a8.w - s * b8.w;
          m4.x = s * a8.x + c * b8.x; m4.y = s * a8.y + c * b8.y;
          m4.z = s * a8.z + c * b8.z; m4.w = s * a8.w + c * b8.w;
          *(float4*)(bp + 64 + 4 * lane) = n4;
          *(float4*)(bq + 64 + 4 * lane) = m4;
        }
        if (lane == 0) {
          nrm[p] = pn - t * d;   // exact Jacobi diagonal update
          nrm[q] = qn + t * d;
          atomicAdd(&nrotsw[sweep], 1);
        }
      }
    }
    __syncthreads();
    if (rr == 98 && nrotsw[sweep] == 0) break;  // uniform read post-barrier
  }

  // ---- exact final scales: sfin[p] = log(max(||b_p||,EPSV)) / ||b_p||^2 ----
  for (int col = g; col < 100; col += 64) {
    const float* bp = B + col * 100;
    float4 a4 = *(const float4*)(bp + 4 * lane);
    float n = a4.x * a4.x + a4.y * a4.y + a4.z * a4.z + a4.w * a4.w;
    if (lane < 9) {
      float4 a8 = *(const float4*)(bp + 64 + 4 * lane);
      n += a8.x * a8.x + a8.y * a8.y + a8.z * a8.z + a8.w * a8.w;
    }
#pragma unroll
    for (int off = 1; off <= 8; off <<= 1) n += __shfl_xor(n, off);
    if (lane == 0) sfin[col] = logf(fmaxf(sqrtf(n), EPSV)) / n;
  }
  __syncthreads();

  // ---- Hf (triu flat) = sum_p sfin[p] * b_p b_p^T ----
  float* Hf = stage;
  {
    float hacc[4][4];
#pragma unroll
    for (int m = 0; m < 4; ++m) hacc[m][0] = hacc[m][1] = hacc[m][2] = hacc[m][3] = 0.f;
    for (int p = 0; p < 100; ++p) {
      float l = sfin[p];
      const float* vr = B + p * 100;
      float vj0 = vr[q4], vj1 = vr[q4 + 32], vj2 = vr[q4 + 64];
      float vj3 = (q4 + 96 < 100) ? vr[q4 + 96] : 0.f;
#pragma unroll
      for (int m = 0; m < 4; ++m) {
        int i = r32 + 32 * m;
        if (i < 100) {
          float vil = vr[i] * l;
          hacc[m][0] += vil * vj0; hacc[m][1] += vil * vj1;
          hacc[m][2] += vil * vj2; hacc[m][3] += vil * vj3;
        }
      }
    }
    __syncthreads();
#pragma unroll
    for (int m = 0; m < 4; ++m) {
      int i = r32 + 32 * m;
      if (i >= 100) continue;
#pragma unroll
      for (int n = 0; n < 4; ++n) {
        int j = q4 + 32 * n;
        if (j < 100 && i <= j) Hf[((201 * i - i * i) >> 1) + (j - i)] = hacc[m][n];
      }
    }
  }
  __syncthreads();

  // ---- classifier ----
  float accc[10];
#pragma unroll
  for (int c = 0; c < 10; ++c) accc[c] = 0.f;
  for (int e = tid; e < 5050; e += 1024) {
    float h = Hf[e];
#pragma unroll
    for (int c = 0; c < 10; ++c) accc[c] += h * Wc[c * 5050 + e];
  }
  const int lane64 = tid & 63, wv = tid >> 6;
#pragma unroll
  for (int c = 0; c < 10; ++c) {
    float v = accc[c];
#pragma unroll
    for (int off = 32; off > 0; off >>= 1) v += __shfl_down(v, off);
    if (lane64 == 0) red[wv][c] = v;
  }
  __syncthreads();
  if (tid < 10) {
    float s = bcv[tid];
#pragma unroll
    for (int w = 0; w < 16; ++w) s += red[w][tid];
    out[b * 10 + tid] = s;
  }
}

extern "C" void kernel_launch(void* const* d_in, const int* in_sizes, int n_in,
                              void* d_out, int out_size, void* d_ws, size_t ws_size,
                              hipStream_t stream) {
  const float* x = (const float*)d_in[0];
  const float* W1 = (const float*)d_in[1];
  const float* W2 = (const float*)d_in[2];
  const float* Wc = (const float*)d_in[3];
  const float* bc = (const float*)d_in[4];
  float* out = (float*)d_out;

  float* W = (float*)d_ws;        // 400*100 floats
  float* Y = W + 40000;           // 256*400*100 floats (~41 MB)

  kA<<<157, 256, 0, stream>>>(W1, W2, W);
  kB<<<dim3(25, 256), 256, 0, stream>>>(x, W, Y);
  kC<<<256, 1024, 0, stream>>>(W, Y, Wc, bc, out);
}